// Round 9
// baseline (314.884 us; speedup 1.0000x reference)
//
#include <hip/hip_runtime.h>
#include <hip/hip_bf16.h>
#include <math.h>

// T=4096, B=4, S=16 -> BS=64, F=64, CH=97 (16 B | 16 C | 1 A | 64 X), K=5.
// Output: (T, B, S) float32, flat index t*64 + bs.
//
// ROUND 9: (1) A channel from MFMA ct=2 col n=0 with bf16-split residual
// (2 extra MFMAs/step) — scalar A path (80 conflicted ds_read_u16/thread)
// removed. (2) float4-vectorized hi/lo staging. (3) k_chunk fused into
// k_conv tail (validated code, LDS sources). (4) k_y: 4 chunks per block.

#define Tn 4096
#define BSn 64
#define Fn 64
#define CHn 97
#define CHP 112   // padded channels for MFMA (7 tiles of 16)
#define Kn 5
#define Nn 16
#define NCn 64

typedef __attribute__((ext_vector_type(8))) short bf16x8;
typedef __attribute__((ext_vector_type(4))) float f32x4;

static __device__ __forceinline__ unsigned short f2bf(float v) {
    __hip_bfloat16 b = __float2bfloat16(v);
    return *reinterpret_cast<unsigned short*>(&b);
}
static __device__ __forceinline__ float bf2f(unsigned short u) {
    unsigned v = ((unsigned)u) << 16;
    return __builtin_bit_cast(float, v);
}

// ---------------- workspace layout (float units) ----------------
// end = OFF_WBL + 2560 = 9,592,832 fl = 38,371,328 B < round-1-validated
// 38,413,568 B envelope (hard bound — round-2 NaN came from exceeding it).
#define OFF_BD   0
#define OFF_CM   (OFF_BD + 4194304)
#define OFF_LAD  (OFF_CM + 4194304)     // unused now (kept to preserve offsets)
#define OFF_XQ   (OFF_LAD + 262144)
#define OFF_DL   (OFF_XQ + 262144)
#define OFF_ACS  (OFF_DL + 262144)
#define OFF_SRED (OFF_ACS + 262144)
#define OFF_CSUM (OFF_SRED + 65536)
#define OFF_SNS  (OFF_CSUM + 4096)
#define OFF_WBH  (OFF_SNS + 65536)      // bf16 [k][112][64] = 35840 us = 17920 fl
#define OFF_WBL  (OFF_WBH + 17920)      // bf16 lo-residual [k][16][64] (ch32..47)

// K0: weight prep: wbh bf16 hi [k][112][64]; wbl bf16 lo for ch 32..47
__global__ __launch_bounds__(256) void k_prep(const float* __restrict__ conv_w,
                                              unsigned short* __restrict__ wbh,
                                              unsigned short* __restrict__ wbl) {
    int idx = blockIdx.x * 256 + threadIdx.x;
    if (idx >= Kn * CHP * Fn) return;
    int f = idx & 63;
    int rest = idx >> 6;
    int ch = rest % CHP;
    int k = rest / CHP;
    float w = (ch < CHn) ? conv_w[(ch * Fn + f) * Kn + k] : 0.f;
    unsigned short hi = f2bf(w);
    wbh[idx] = hi;
    if (ch >= 32 && ch < 48)
        wbl[(k * 16 + (ch - 32)) * 64 + f] = f2bf(w - bf2f(hi));
}

// K1: MFMA conv (all 97 ch; ct2 tile split-corrected) + epilogue from regs
//     + fused chunk-state tail. One block = (ci, bs), 256 thr = 4 waves.
__global__ __launch_bounds__(256) void k_conv(
    const float* __restrict__ x, const unsigned short* __restrict__ wbh,
    const unsigned short* __restrict__ wbl,
    const float* __restrict__ conv_b, const float* __restrict__ pass_w,
    const float* __restrict__ pass_b, const float* __restrict__ red_w,
    const float* __restrict__ red_b, const float* __restrict__ dtp,
    float* __restrict__ Bd_t, float* __restrict__ Cm_t,
    float* __restrict__ xq_ws, float* __restrict__ DL_ws,
    float* __restrict__ Acs_ws, float* __restrict__ sred_ws,
    float* __restrict__ csum_ws) {
    const int ci = blockIdx.x, bs = blockIdx.y;
    const int tid = threadIdx.x;
    const int wv = tid >> 6, lane = tid & 63;
    const int qd = lane >> 4, n = lane & 15;

    __shared__ alignas(16) unsigned short xsb[68 * 72];  // bf16 hi tile, pitch 72
    __shared__ alignas(16) unsigned short xlo[68 * 72];  // bf16 lo tile
    __shared__ float BtS[64 * 17];                       // Bd rows for fused tail
    __shared__ float redx[64 * 17];                      // xq reduction
    __shared__ float redd[64 * 17];                      // Dx reduction
    __shared__ float zAS[64], lAdS[64], fac[64], xqS[64];
    __shared__ float acsS[64], vvS[64], partS[4][16];

    // ---- vectorized hi/lo staging: 68 rows x 16 float4 groups
    for (int idx = tid; idx < 68 * 16; idx += 256) {
        int tt = idx >> 4, fq = (idx & 15) * 4;
        int t = ci * 64 - 4 + tt;
        float4 v = (t >= 0) ? *(const float4*)&x[(t * 64 + bs) * 64 + fq]
                            : make_float4(0.f, 0.f, 0.f, 0.f);
        ushort4 h, lo;
        h.x = f2bf(v.x); lo.x = f2bf(v.x - bf2f(h.x));
        h.y = f2bf(v.y); lo.y = f2bf(v.y - bf2f(h.y));
        h.z = f2bf(v.z); lo.z = f2bf(v.z - bf2f(h.z));
        h.w = f2bf(v.w); lo.w = f2bf(v.w - bf2f(h.w));
        *(ushort4*)&xsb[tt * 72 + fq] = h;
        *(ushort4*)&xlo[tt * 72 + fq] = lo;
    }
    for (int idx = tid; idx < 68 * 2; idx += 256) {  // zero pad cols 64..71
        int tt = idx >> 1, c = (idx & 1) * 4;
        *(ushort4*)&xsb[tt * 72 + 64 + c] = (ushort4){0, 0, 0, 0};
        *(ushort4*)&xlo[tt * 72 + 64 + c] = (ushort4){0, 0, 0, 0};
    }
    __syncthreads();

    // ---- Dx partials (skip path): thread = (tl, cg), f = cg*4..cg*4+3
    {
        const int tl = tid & 15, cg = tid >> 4;
        float4 pw = *(const float4*)&pass_w[cg * 4];
#pragma unroll
        for (int j = 0; j < 4; ++j) {
            const unsigned short* xr = &xsb[(tl + 16 * j + 4) * 72 + cg * 4];
            redd[(tl + 16 * j) * 17 + cg] =
                bf2f(xr[0]) * pw.x + bf2f(xr[1]) * pw.y +
                bf2f(xr[2]) * pw.z + bf2f(xr[3]) * pw.w;
        }
    }

    // ---- MFMA GEMM (HW-verified fragment path): K = 5 taps x 64 f
    f32x4 acc[7];
#pragma unroll
    for (int ct = 0; ct < 7; ++ct) acc[ct] = (f32x4){0.f, 0.f, 0.f, 0.f};
#pragma unroll 1
    for (int s = 0; s < 10; ++s) {
        const int k = s >> 1;
        const int f0 = 32 * (s & 1) + qd * 8;
        bf16x8 av = *(const bf16x8*)&xsb[(16 * wv + n + k) * 72 + f0];
#pragma unroll
        for (int ct = 0; ct < 7; ++ct) {
            bf16x8 bv = *(const bf16x8*)&wbh[((k * CHP + 16 * ct + n) << 6) + f0];
            acc[ct] = __builtin_amdgcn_mfma_f32_16x16x32_bf16(av, bv, acc[ct], 0, 0, 0);
        }
        // split-residual correction for ct=2 tile (ch 32..47): makes the A
        // channel (ch32) ~f32-exact; drops only x_lo*w_lo (~2^-18 rel).
        bf16x8 al = *(const bf16x8*)&xlo[(16 * wv + n + k) * 72 + f0];
        bf16x8 bh2 = *(const bf16x8*)&wbh[((k * CHP + 32 + n) << 6) + f0];
        bf16x8 bl2 = *(const bf16x8*)&wbl[((k * 16 + n) << 6) + f0];
        acc[2] = __builtin_amdgcn_mfma_f32_16x16x32_bf16(al, bh2, acc[2], 0, 0, 0);
        acc[2] = __builtin_amdgcn_mfma_f32_16x16x32_bf16(av, bl2, acc[2], 0, 0, 0);
    }
    // A channel = ct2 col n==0 (D layout: row = 16wv+4qd+reg, col = n)
    if (n == 0) {
#pragma unroll
        for (int reg = 0; reg < 4; ++reg)
            zAS[16 * wv + 4 * qd + reg] = acc[2][reg];
    }
    __syncthreads();

    // ---- A transform -> lAd, fac
    if (tid < 64) {
        const float dt = log1pf(expf(dtp[0])) + 0.01f;
        float z = zAS[tid] + conv_b[32];
        float a = z + 1.f / (1.f + __expf(-z));
        float An = -fabsf(a);
        float lAd = dt * An;
        lAdS[tid] = lAd;
        fac[tid] = (__expf(lAd) - 1.f) / (An + 1e-9f);
    }
    __syncthreads();

    // ---- epilogue from acc regs: lane owns col ch=16ct+n, rows 16wv+4qd+reg
    float px[4] = {0.f, 0.f, 0.f, 0.f};
#pragma unroll
    for (int ct = 0; ct < 7; ++ct) {
        int ch = 16 * ct + n;
        if (ch < CHn) {
            float cb = conv_b[ch];
            float rw = (ch >= 33) ? red_w[ch - 33] : 0.f;
#pragma unroll
            for (int reg = 0; reg < 4; ++reg) {
                int l = 16 * wv + 4 * qd + reg;
                float z = acc[ct][reg] + cb;
                float a = z + 1.f / (1.f + __expf(-z));
                if (ct == 0) {
                    float bdv = a * fac[l];
                    Bd_t[((bs * 64 + ci) * 64 + l) * 16 + n] = bdv;
                    BtS[l * 17 + n] = bdv;
                } else if (ct == 1) {
                    Cm_t[((bs * 64 + ci) * 64 + l) * 16 + n] = a;
                } else if (ch >= 33) {  // X channels 33..96 (ch32=A skipped)
                    px[reg] += a * rw;
                }
            }
        }
    }
#pragma unroll
    for (int reg = 0; reg < 4; ++reg)
        redx[(16 * wv + 4 * qd + reg) * 17 + n] = px[reg];
    __syncthreads();

    if (tid < 64) {
        float s = 0.f;
#pragma unroll
        for (int c2 = 0; c2 < 16; ++c2) s += redx[tid * 17 + c2];
        xqS[tid] = s;
        xq_ws[bs * Tn + ci * 64 + tid] = s;
    } else if (tid < 128) {
        int l = tid - 64;
        float s = 0.f;
#pragma unroll
        for (int c2 = 0; c2 < 16; ++c2) s += redd[l * 17 + c2];
        float Dx = s + pass_b[0];
        float DL = (Dx >= 0.f) ? Dx : 0.01f * Dx;
        DL_ws[bs * Tn + ci * 64 + l] = DL + red_b[0];
    }
    __syncthreads();

    // ---- fused chunk tail (validated k_chunk logic, LDS sources)
    if (tid < 64) {
        float s = 0.f;
        for (int k2 = 0; k2 < 64; ++k2) {
            float v = lAdS[k2];
            if (k2 <= tid) s += v;
        }
        acsS[tid] = s;
        Acs_ws[bs * Tn + ci * 64 + tid] = s;
    }
    __syncthreads();
    if (tid < 64) {
        float tot = acsS[63];
        float ds = __expf(fmaxf(tot - acsS[tid], -20.f));
        vvS[tid] = ds * xqS[tid];
    }
    __syncthreads();
    if (tid < 64) {
        int n2 = tid & 15, q = tid >> 4;
        float p = 0.f;
#pragma unroll
        for (int i = 0; i < 16; ++i)
            p += BtS[(q * 16 + i) * 17 + n2] * vvS[q * 16 + i];
        partS[q][n2] = p;
    }
    __syncthreads();
    if (tid < 16)
        sred_ws[(bs * 64 + ci) * 16 + tid] =
            partS[0][tid] + partS[1][tid] + partS[2][tid] + partS[3][tid];
    if (tid == 0) csum_ws[bs * 64 + ci] = acsS[63];
}

// K3: inter-chunk scan of reduced states (N=16 per (b,s))
__global__ __launch_bounds__(256) void k_scan(const float* __restrict__ sred_ws,
                                              const float* __restrict__ csum_ws,
                                              float* __restrict__ sns_ws) {
    int g = blockIdx.x * 256 + threadIdx.x;
    if (g >= BSn * Nn) return;
    int bs = g >> 4, n = g & 15;
    float ns = 0.f;
    for (int ci = 0; ci < NCn; ++ci) {
        sns_ws[(bs * 64 + ci) * 16 + n] = ns;
        float d = __expf(csum_ws[bs * 64 + ci]);
        ns = d * ns + sred_ws[(bs * 64 + ci) * 16 + n];
    }
}

// K4: y[l] = sum_m L[l,m]*(C[l]·B[m])*xq[m] + exp(Acs[l])*(C[l]·sns) + DL
//     4 chunks per block: wave wv handles ci = 4*bx + wv, l = lane.
__global__ __launch_bounds__(256) void k_y(
    const float* __restrict__ Cm_t, const float* __restrict__ Bd_t,
    const float* __restrict__ xq_ws, const float* __restrict__ Acs_ws,
    const float* __restrict__ sns_ws, const float* __restrict__ DL_ws,
    float* __restrict__ out) {
    const int bs = blockIdx.y;
    const int tid = threadIdx.x;
    const int wv = tid >> 6, l = tid & 63;
    const int ci = blockIdx.x * 4 + wv;
    __shared__ float Bt[4][64 * 17], xv[4][64], ac[4][64], sn[4][16];
    const int base = bs * Tn + ci * 64;

    xv[wv][l] = xq_ws[base + l];
    ac[wv][l] = Acs_ws[base + l];
    if (l < 16) sn[wv][l] = sns_ws[(bs * 64 + ci) * 16 + l];
    const float4* brow = (const float4*)&Bd_t[((bs * 64 + ci) * 64 + l) * 16];
    float4 b0 = brow[0], b1 = brow[1], b2 = brow[2], b3 = brow[3];
    float* bt = &Bt[wv][l * 17];
    bt[0] = b0.x;  bt[1] = b0.y;  bt[2] = b0.z;  bt[3] = b0.w;
    bt[4] = b1.x;  bt[5] = b1.y;  bt[6] = b1.z;  bt[7] = b1.w;
    bt[8] = b2.x;  bt[9] = b2.y;  bt[10] = b2.z; bt[11] = b2.w;
    bt[12] = b3.x; bt[13] = b3.y; bt[14] = b3.z; bt[15] = b3.w;
    const float4* crow = (const float4*)&Cm_t[((bs * 64 + ci) * 64 + l) * 16];
    float4 c0 = crow[0], c1 = crow[1], c2 = crow[2], c3 = crow[3];
    __syncthreads();

    const float acl = ac[wv][l];
    float y = 0.f;
    for (int m = 0; m < 64; ++m) {
        const float* br = &Bt[wv][m * 17];
        float g = c0.x * br[0] + c0.y * br[1] + c0.z * br[2] + c0.w * br[3] +
                  c1.x * br[4] + c1.y * br[5] + c1.z * br[6] + c1.w * br[7] +
                  c2.x * br[8] + c2.y * br[9] + c2.z * br[10] + c2.w * br[11] +
                  c3.x * br[12] + c3.y * br[13] + c3.z * br[14] + c3.w * br[15];
        float arg = (m <= l) ? fmaxf(acl - ac[wv][m], -20.f) : -20.f;
        y += __expf(arg) * g * xv[wv][m];
    }
    const float* s = sn[wv];
    float go = c0.x * s[0] + c0.y * s[1] + c0.z * s[2] + c0.w * s[3] +
               c1.x * s[4] + c1.y * s[5] + c1.z * s[6] + c1.w * s[7] +
               c2.x * s[8] + c2.y * s[9] + c2.z * s[10] + c2.w * s[11] +
               c3.x * s[12] + c3.y * s[13] + c3.z * s[14] + c3.w * s[15];
    y += __expf(acl) * go;

    out[(ci * 64 + l) * 64 + bs] = y + DL_ws[base + l];
}

extern "C" void kernel_launch(void* const* d_in, const int* in_sizes, int n_in,
                              void* d_out, int out_size, void* d_ws,
                              size_t ws_size, hipStream_t stream) {
    const float* x = (const float*)d_in[0];
    const float* conv_w = (const float*)d_in[1];
    const float* conv_b = (const float*)d_in[2];
    const float* pass_w = (const float*)d_in[3];
    const float* pass_b = (const float*)d_in[4];
    const float* red_w = (const float*)d_in[5];
    const float* red_b = (const float*)d_in[6];
    const float* dtp = (const float*)d_in[7];
    float* out = (float*)d_out;
    float* W = (float*)d_ws;
    (void)in_sizes; (void)n_in; (void)out_size; (void)ws_size;

    float* Bd_t = W + OFF_BD;
    float* Cm_t = W + OFF_CM;
    float* xq_ws = W + OFF_XQ;
    float* DL_ws = W + OFF_DL;
    float* Acs_ws = W + OFF_ACS;
    float* sred_ws = W + OFF_SRED;
    float* csum_ws = W + OFF_CSUM;
    float* sns_ws = W + OFF_SNS;
    unsigned short* wbh = (unsigned short*)(W + OFF_WBH);
    unsigned short* wbl = (unsigned short*)(W + OFF_WBL);

    k_prep<<<dim3((Kn * CHP * Fn + 255) / 256), dim3(256), 0, stream>>>(conv_w, wbh, wbl);
    k_conv<<<dim3(NCn, BSn), dim3(256), 0, stream>>>(
        x, wbh, wbl, conv_b, pass_w, pass_b, red_w, red_b, dtp,
        Bd_t, Cm_t, xq_ws, DL_ws, Acs_ws, sred_ws, csum_ws);
    k_scan<<<dim3(4), dim3(256), 0, stream>>>(sred_ws, csum_ws, sns_ws);
    k_y<<<dim3(NCn / 4, BSn), dim3(256), 0, stream>>>(
        Cm_t, Bd_t, xq_ws, Acs_ws, sns_ws, DL_ws, out);
}

// Round 10
// 292.029 us; speedup vs baseline: 1.0783x; 1.0783x over previous
//
#include <hip/hip_runtime.h>
#include <hip/hip_bf16.h>
#include <math.h>

// T=4096, B=4, S=16 -> BS=64, F=64, CH=97 (16 B | 16 C | 1 A | 64 X), K=5.
// Output: (T, B, S) float32, flat index t*64 + bs.
//
// ROUND 10: round 9 minus the fused chunk tail (re-separated k_chunk —
// fusion cost +18 us of serialized barrier time), plus: batched staging
// loads (5 float4 in flight -> one wait), xlo/redx/redd LDS union with
// Dx-partials moved post-MFMA (LDS 34.8 -> ~20 KB, occupancy up),
// unroll-2 s-loop to batch weight loads.

#define Tn 4096
#define BSn 64
#define Fn 64
#define CHn 97
#define CHP 112   // padded channels for MFMA (7 tiles of 16)
#define Kn 5
#define Nn 16
#define NCn 64

typedef __attribute__((ext_vector_type(8))) short bf16x8;
typedef __attribute__((ext_vector_type(4))) float f32x4;

static __device__ __forceinline__ unsigned short f2bf(float v) {
    __hip_bfloat16 b = __float2bfloat16(v);
    return *reinterpret_cast<unsigned short*>(&b);
}
static __device__ __forceinline__ float bf2f(unsigned short u) {
    unsigned v = ((unsigned)u) << 16;
    return __builtin_bit_cast(float, v);
}

// ---------------- workspace layout (float units) ----------------
// end = OFF_WBL + 2560 = 9,592,832 fl = 38,371,328 B < round-1-validated
// 38,413,568 B envelope (hard bound — round-2 NaN came from exceeding it).
#define OFF_BD   0
#define OFF_CM   (OFF_BD + 4194304)
#define OFF_LAD  (OFF_CM + 4194304)
#define OFF_XQ   (OFF_LAD + 262144)
#define OFF_DL   (OFF_XQ + 262144)
#define OFF_ACS  (OFF_DL + 262144)
#define OFF_SRED (OFF_ACS + 262144)
#define OFF_CSUM (OFF_SRED + 65536)
#define OFF_SNS  (OFF_CSUM + 4096)
#define OFF_WBH  (OFF_SNS + 65536)      // bf16 [k][112][64] = 35840 us = 17920 fl
#define OFF_WBL  (OFF_WBH + 17920)      // bf16 lo-residual [k][16][64] (ch32..47)

// K0: weight prep: wbh bf16 hi [k][112][64]; wbl bf16 lo for ch 32..47
__global__ __launch_bounds__(256) void k_prep(const float* __restrict__ conv_w,
                                              unsigned short* __restrict__ wbh,
                                              unsigned short* __restrict__ wbl) {
    int idx = blockIdx.x * 256 + threadIdx.x;
    if (idx >= Kn * CHP * Fn) return;
    int f = idx & 63;
    int rest = idx >> 6;
    int ch = rest % CHP;
    int k = rest / CHP;
    float w = (ch < CHn) ? conv_w[(ch * Fn + f) * Kn + k] : 0.f;
    unsigned short hi = f2bf(w);
    wbh[idx] = hi;
    if (ch >= 32 && ch < 48)
        wbl[(k * 16 + (ch - 32)) * 64 + f] = f2bf(w - bf2f(hi));
}

// K1: MFMA conv (all 97 ch; ct2 split-corrected) + epilogue from registers.
// One block = (ci, bs), 256 thr = 4 waves; wave wv owns rows 16wv..16wv+15.
__global__ __launch_bounds__(256) void k_conv(
    const float* __restrict__ x, const unsigned short* __restrict__ wbh,
    const unsigned short* __restrict__ wbl,
    const float* __restrict__ conv_b, const float* __restrict__ pass_w,
    const float* __restrict__ pass_b, const float* __restrict__ red_w,
    const float* __restrict__ red_b, const float* __restrict__ dtp,
    float* __restrict__ Bd_t, float* __restrict__ Cm_t,
    float* __restrict__ lAd_ws, float* __restrict__ xq_ws,
    float* __restrict__ DL_ws) {
    const int ci = blockIdx.x, bs = blockIdx.y;
    const int tid = threadIdx.x;
    const int wv = tid >> 6, lane = tid & 63;
    const int qd = lane >> 4, n = lane & 15;

    __shared__ alignas(16) unsigned short xsb[68 * 72];  // bf16 hi tile, pitch 72
    // union: phase-1 = xlo (bf16 lo tile, 9792 B); phase-2 = redd+redx (8704 B)
    __shared__ alignas(16) unsigned char upool[68 * 72 * 2];
    unsigned short* xlo = (unsigned short*)upool;
    float* redd = (float*)upool;                 // Dx reduction [64][17]
    float* redx = (float*)(upool + 4352);        // xq reduction [64][17]
    __shared__ float zAS[64], fac[64];

    // ---- batched staging: 5 independent float4 loads -> one wait -> store
    float4 v[5];
#pragma unroll
    for (int it = 0; it < 5; ++it) {
        int idx = tid + it * 256;
        int tt = idx >> 4, fq = (idx & 15) * 4;
        int t = ci * 64 - 4 + tt;
        v[it] = (idx < 68 * 16 && t >= 0)
                    ? *(const float4*)&x[(t * 64 + bs) * 64 + fq]
                    : make_float4(0.f, 0.f, 0.f, 0.f);
    }
#pragma unroll
    for (int it = 0; it < 5; ++it) {
        int idx = tid + it * 256;
        if (idx < 68 * 16) {
            int tt = idx >> 4, fq = (idx & 15) * 4;
            ushort4 h, lo;
            h.x = f2bf(v[it].x); lo.x = f2bf(v[it].x - bf2f(h.x));
            h.y = f2bf(v[it].y); lo.y = f2bf(v[it].y - bf2f(h.y));
            h.z = f2bf(v[it].z); lo.z = f2bf(v[it].z - bf2f(h.z));
            h.w = f2bf(v[it].w); lo.w = f2bf(v[it].w - bf2f(h.w));
            *(ushort4*)&xsb[tt * 72 + fq] = h;
            *(ushort4*)&xlo[tt * 72 + fq] = lo;
        }
    }
    for (int idx = tid; idx < 68 * 2; idx += 256) {  // zero pad cols 64..71
        int tt = idx >> 1, c = (idx & 1) * 4;
        *(ushort4*)&xsb[tt * 72 + 64 + c] = (ushort4){0, 0, 0, 0};
        *(ushort4*)&xlo[tt * 72 + 64 + c] = (ushort4){0, 0, 0, 0};
    }
    __syncthreads();

    // ---- MFMA GEMM (HW-verified fragment path): K = 5 taps x 64 f
    f32x4 acc[7];
#pragma unroll
    for (int ct = 0; ct < 7; ++ct) acc[ct] = (f32x4){0.f, 0.f, 0.f, 0.f};
#pragma unroll 2
    for (int s = 0; s < 10; ++s) {
        const int k = s >> 1;
        const int f0 = 32 * (s & 1) + qd * 8;
        bf16x8 av = *(const bf16x8*)&xsb[(16 * wv + n + k) * 72 + f0];
#pragma unroll
        for (int ct = 0; ct < 7; ++ct) {
            bf16x8 bv = *(const bf16x8*)&wbh[((k * CHP + 16 * ct + n) << 6) + f0];
            acc[ct] = __builtin_amdgcn_mfma_f32_16x16x32_bf16(av, bv, acc[ct], 0, 0, 0);
        }
        // split-residual correction for ct=2 tile (ch 32..47): makes the A
        // channel (ch32) ~f32-exact; drops only x_lo*w_lo (~2^-18 rel).
        bf16x8 al = *(const bf16x8*)&xlo[(16 * wv + n + k) * 72 + f0];
        bf16x8 bh2 = *(const bf16x8*)&wbh[((k * CHP + 32 + n) << 6) + f0];
        bf16x8 bl2 = *(const bf16x8*)&wbl[((k * 16 + n) << 6) + f0];
        acc[2] = __builtin_amdgcn_mfma_f32_16x16x32_bf16(al, bh2, acc[2], 0, 0, 0);
        acc[2] = __builtin_amdgcn_mfma_f32_16x16x32_bf16(av, bl2, acc[2], 0, 0, 0);
    }
    // A channel = ct2 col n==0 (D layout: row = 16wv+4qd+reg, col = n)
    if (n == 0) {
#pragma unroll
        for (int reg = 0; reg < 4; ++reg)
            zAS[16 * wv + 4 * qd + reg] = acc[2][reg];
    }
    __syncthreads();  // zAS ready; also ends xlo lifetime (union -> redd/redx)

    // ---- Dx partials (reads xsb, still live): thread = (tl, cg)
    {
        const int tl = tid & 15, cg = tid >> 4;
        float4 pw = *(const float4*)&pass_w[cg * 4];
#pragma unroll
        for (int j = 0; j < 4; ++j) {
            const unsigned short* xr = &xsb[(tl + 16 * j + 4) * 72 + cg * 4];
            redd[(tl + 16 * j) * 17 + cg] =
                bf2f(xr[0]) * pw.x + bf2f(xr[1]) * pw.y +
                bf2f(xr[2]) * pw.z + bf2f(xr[3]) * pw.w;
        }
    }
    // ---- A transform -> lAd, fac
    if (tid < 64) {
        const float dt = log1pf(expf(dtp[0])) + 0.01f;
        float z = zAS[tid] + conv_b[32];
        float a = z + 1.f / (1.f + __expf(-z));
        float An = -fabsf(a);
        float lAd = dt * An;
        lAd_ws[bs * Tn + ci * 64 + tid] = lAd;
        fac[tid] = (__expf(lAd) - 1.f) / (An + 1e-9f);
    }
    __syncthreads();

    // ---- epilogue from acc regs: lane owns col ch=16ct+n, rows 16wv+4qd+reg
    float px[4] = {0.f, 0.f, 0.f, 0.f};
#pragma unroll
    for (int ct = 0; ct < 7; ++ct) {
        int ch = 16 * ct + n;
        if (ch < CHn) {
            float cb = conv_b[ch];
            float rw = (ch >= 33) ? red_w[ch - 33] : 0.f;
#pragma unroll
            for (int reg = 0; reg < 4; ++reg) {
                int l = 16 * wv + 4 * qd + reg;
                float z = acc[ct][reg] + cb;
                float a = z + 1.f / (1.f + __expf(-z));
                if (ct == 0) {
                    Bd_t[((bs * 64 + ci) * 64 + l) * 16 + n] = a * fac[l];
                } else if (ct == 1) {
                    Cm_t[((bs * 64 + ci) * 64 + l) * 16 + n] = a;
                } else if (ch >= 33) {  // X channels 33..96 (ch32=A skipped)
                    px[reg] += a * rw;
                }
            }
        }
    }
#pragma unroll
    for (int reg = 0; reg < 4; ++reg)
        redx[(16 * wv + 4 * qd + reg) * 17 + n] = px[reg];
    __syncthreads();

    if (tid < 64) {
        float s = 0.f;
#pragma unroll
        for (int c2 = 0; c2 < 16; ++c2) s += redx[tid * 17 + c2];
        xq_ws[bs * Tn + ci * 64 + tid] = s;
    } else if (tid < 128) {
        int l = tid - 64;
        float s = 0.f;
#pragma unroll
        for (int c2 = 0; c2 < 16; ++c2) s += redd[l * 17 + c2];
        float Dx = s + pass_b[0];
        float DL = (Dx >= 0.f) ? Dx : 0.01f * Dx;
        DL_ws[bs * Tn + ci * 64 + l] = DL + red_b[0];
    }
}

// K2: per (bs, ci) tile: cumsum of lAd, decay-weighted reduced chunk state
// (validated round-8 kernel, verbatim)
__global__ __launch_bounds__(64) void k_chunk(
    const float* __restrict__ lAd_ws, const float* __restrict__ xq_ws,
    const float* __restrict__ Bd_t, float* __restrict__ Acs_ws,
    float* __restrict__ sred_ws, float* __restrict__ csum_ws) {
    const int ci = blockIdx.x, bs = blockIdx.y, l = threadIdx.x;
    __shared__ float aL[64], acs[64], vv[64], Bt[64 * 17], part[4][16];
    const int base = bs * Tn + ci * 64;

    aL[l] = lAd_ws[base + l];
    const float4* brow = (const float4*)&Bd_t[((bs * 64 + ci) * 64 + l) * 16];
    float4 b0 = brow[0], b1 = brow[1], b2 = brow[2], b3 = brow[3];
    Bt[l * 17 + 0] = b0.x;  Bt[l * 17 + 1] = b0.y;  Bt[l * 17 + 2] = b0.z;  Bt[l * 17 + 3] = b0.w;
    Bt[l * 17 + 4] = b1.x;  Bt[l * 17 + 5] = b1.y;  Bt[l * 17 + 6] = b1.z;  Bt[l * 17 + 7] = b1.w;
    Bt[l * 17 + 8] = b2.x;  Bt[l * 17 + 9] = b2.y;  Bt[l * 17 + 10] = b2.z; Bt[l * 17 + 11] = b2.w;
    Bt[l * 17 + 12] = b3.x; Bt[l * 17 + 13] = b3.y; Bt[l * 17 + 14] = b3.z; Bt[l * 17 + 15] = b3.w;
    __syncthreads();

    float s = 0.f;
    for (int k2 = 0; k2 < 64; ++k2) {
        float v = aL[k2];
        if (k2 <= l) s += v;
    }
    acs[l] = s;
    Acs_ws[base + l] = s;
    __syncthreads();

    float tot = acs[63];
    float ds = __expf(fmaxf(tot - s, -20.f));
    vv[l] = ds * xq_ws[base + l];
    __syncthreads();

    int n = l & 15, q = l >> 4;
    float p = 0.f;
#pragma unroll
    for (int i = 0; i < 16; ++i) p += Bt[(q * 16 + i) * 17 + n] * vv[q * 16 + i];
    part[q][n] = p;
    __syncthreads();
    if (l < 16)
        sred_ws[(bs * 64 + ci) * 16 + l] =
            part[0][l] + part[1][l] + part[2][l] + part[3][l];
    if (l == 0) csum_ws[bs * 64 + ci] = tot;
}

// K3: inter-chunk scan of reduced states (N=16 per (b,s))
__global__ __launch_bounds__(256) void k_scan(const float* __restrict__ sred_ws,
                                              const float* __restrict__ csum_ws,
                                              float* __restrict__ sns_ws) {
    int g = blockIdx.x * 256 + threadIdx.x;
    if (g >= BSn * Nn) return;
    int bs = g >> 4, n = g & 15;
    float ns = 0.f;
    for (int ci = 0; ci < NCn; ++ci) {
        sns_ws[(bs * 64 + ci) * 16 + n] = ns;
        float d = __expf(csum_ws[bs * 64 + ci]);
        ns = d * ns + sred_ws[(bs * 64 + ci) * 16 + n];
    }
}

// K4: y[l] = sum_m L[l,m]*(C[l]·B[m])*xq[m] + exp(Acs[l])*(C[l]·sns) + DL
//     4 chunks per block: wave wv handles ci = 4*bx + wv, l = lane.
__global__ __launch_bounds__(256) void k_y(
    const float* __restrict__ Cm_t, const float* __restrict__ Bd_t,
    const float* __restrict__ xq_ws, const float* __restrict__ Acs_ws,
    const float* __restrict__ sns_ws, const float* __restrict__ DL_ws,
    float* __restrict__ out) {
    const int bs = blockIdx.y;
    const int tid = threadIdx.x;
    const int wv = tid >> 6, l = tid & 63;
    const int ci = blockIdx.x * 4 + wv;
    __shared__ float Bt[4][64 * 17], xv[4][64], ac[4][64], sn[4][16];
    const int base = bs * Tn + ci * 64;

    xv[wv][l] = xq_ws[base + l];
    ac[wv][l] = Acs_ws[base + l];
    if (l < 16) sn[wv][l] = sns_ws[(bs * 64 + ci) * 16 + l];
    const float4* brow = (const float4*)&Bd_t[((bs * 64 + ci) * 64 + l) * 16];
    float4 b0 = brow[0], b1 = brow[1], b2 = brow[2], b3 = brow[3];
    float* bt = &Bt[wv][l * 17];
    bt[0] = b0.x;  bt[1] = b0.y;  bt[2] = b0.z;  bt[3] = b0.w;
    bt[4] = b1.x;  bt[5] = b1.y;  bt[6] = b1.z;  bt[7] = b1.w;
    bt[8] = b2.x;  bt[9] = b2.y;  bt[10] = b2.z; bt[11] = b2.w;
    bt[12] = b3.x; bt[13] = b3.y; bt[14] = b3.z; bt[15] = b3.w;
    const float4* crow = (const float4*)&Cm_t[((bs * 64 + ci) * 64 + l) * 16];
    float4 c0 = crow[0], c1 = crow[1], c2 = crow[2], c3 = crow[3];
    __syncthreads();

    const float acl = ac[wv][l];
    float y = 0.f;
    for (int m = 0; m < 64; ++m) {
        const float* br = &Bt[wv][m * 17];
        float g = c0.x * br[0] + c0.y * br[1] + c0.z * br[2] + c0.w * br[3] +
                  c1.x * br[4] + c1.y * br[5] + c1.z * br[6] + c1.w * br[7] +
                  c2.x * br[8] + c2.y * br[9] + c2.z * br[10] + c2.w * br[11] +
                  c3.x * br[12] + c3.y * br[13] + c3.z * br[14] + c3.w * br[15];
        float arg = (m <= l) ? fmaxf(acl - ac[wv][m], -20.f) : -20.f;
        y += __expf(arg) * g * xv[wv][m];
    }
    const float* s = sn[wv];
    float go = c0.x * s[0] + c0.y * s[1] + c0.z * s[2] + c0.w * s[3] +
               c1.x * s[4] + c1.y * s[5] + c1.z * s[6] + c1.w * s[7] +
               c2.x * s[8] + c2.y * s[9] + c2.z * s[10] + c2.w * s[11] +
               c3.x * s[12] + c3.y * s[13] + c3.z * s[14] + c3.w * s[15];
    y += __expf(acl) * go;

    out[(ci * 64 + l) * 64 + bs] = y + DL_ws[base + l];
}

extern "C" void kernel_launch(void* const* d_in, const int* in_sizes, int n_in,
                              void* d_out, int out_size, void* d_ws,
                              size_t ws_size, hipStream_t stream) {
    const float* x = (const float*)d_in[0];
    const float* conv_w = (const float*)d_in[1];
    const float* conv_b = (const float*)d_in[2];
    const float* pass_w = (const float*)d_in[3];
    const float* pass_b = (const float*)d_in[4];
    const float* red_w = (const float*)d_in[5];
    const float* red_b = (const float*)d_in[6];
    const float* dtp = (const float*)d_in[7];
    float* out = (float*)d_out;
    float* W = (float*)d_ws;
    (void)in_sizes; (void)n_in; (void)out_size; (void)ws_size;

    float* Bd_t = W + OFF_BD;
    float* Cm_t = W + OFF_CM;
    float* lAd_ws = W + OFF_LAD;
    float* xq_ws = W + OFF_XQ;
    float* DL_ws = W + OFF_DL;
    float* Acs_ws = W + OFF_ACS;
    float* sred_ws = W + OFF_SRED;
    float* csum_ws = W + OFF_CSUM;
    float* sns_ws = W + OFF_SNS;
    unsigned short* wbh = (unsigned short*)(W + OFF_WBH);
    unsigned short* wbl = (unsigned short*)(W + OFF_WBL);

    k_prep<<<dim3((Kn * CHP * Fn + 255) / 256), dim3(256), 0, stream>>>(conv_w, wbh, wbl);
    k_conv<<<dim3(NCn, BSn), dim3(256), 0, stream>>>(
        x, wbh, wbl, conv_b, pass_w, pass_b, red_w, red_b, dtp,
        Bd_t, Cm_t, lAd_ws, xq_ws, DL_ws);
    k_chunk<<<dim3(NCn, BSn), dim3(64), 0, stream>>>(
        lAd_ws, xq_ws, Bd_t, Acs_ws, sred_ws, csum_ws);
    k_scan<<<dim3(4), dim3(256), 0, stream>>>(sred_ws, csum_ws, sns_ws);
    k_y<<<dim3(NCn / 4, BSn), dim3(256), 0, stream>>>(
        Cm_t, Bd_t, xq_ws, Acs_ws, sns_ws, DL_ws, out);
}